// Round 1
// baseline (30.134 us; speedup 1.0000x reference)
//
#include <hip/hip_runtime.h>

#define B_ 64
#define N_ 900
#define C_ 16
#define NCHAR_ 75
#define L_ 8

// K1: one thread per (b,n). Computes the full matching cost.
__global__ __launch_bounds__(64) void cost_kernel(
    const float* __restrict__ logits,   // [B,N,C]
    const float* __restrict__ boxes,    // [B,N,8]
    const float* __restrict__ ps,       // [B,NCHAR,N,L]
    const float* __restrict__ tgt,      // [B,4]
    const int*   __restrict__ ptype,    // [B]
    const int*   __restrict__ lps,      // [B,L]
    float* __restrict__ cost)           // [B,N]
{
    int idx = blockIdx.x * 64 + threadIdx.x;
    if (idx >= B_ * N_) return;
    int b = idx / N_;
    int n = idx - b * N_;

    // ---------- string CE: lse over 75 chars per l, minus target logit ----------
    int tl[L_];
    {
        const int4* lp4 = (const int4*)(lps + b * L_);
        int4 q0 = lp4[0], q1 = lp4[1];
        tl[0]=q0.x; tl[1]=q0.y; tl[2]=q0.z; tl[3]=q0.w;
        tl[4]=q1.x; tl[5]=q1.y; tl[6]=q1.z; tl[7]=q1.w;
    }
    float s[L_], tv[L_];
    #pragma unroll
    for (int l = 0; l < L_; ++l) { s[l] = 0.0f; tv[l] = 0.0f; }

    const float* base = ps + ((size_t)b * NCHAR_ * N_ + n) * L_;
    #pragma unroll 5
    for (int c = 0; c < NCHAR_; ++c) {
        const float4* p4 = (const float4*)(base + (size_t)c * (N_ * L_));
        float4 a = p4[0];
        float4 d = p4[1];
        float v0 = a.x, v1 = a.y, v2 = a.z, v3 = a.w;
        float v4 = d.x, v5 = d.y, v6 = d.z, v7 = d.w;
        s[0] += __expf(v0); tv[0] = (c == tl[0]) ? v0 : tv[0];
        s[1] += __expf(v1); tv[1] = (c == tl[1]) ? v1 : tv[1];
        s[2] += __expf(v2); tv[2] = (c == tl[2]) ? v2 : tv[2];
        s[3] += __expf(v3); tv[3] = (c == tl[3]) ? v3 : tv[3];
        s[4] += __expf(v4); tv[4] = (c == tl[4]) ? v4 : tv[4];
        s[5] += __expf(v5); tv[5] = (c == tl[5]) ? v5 : tv[5];
        s[6] += __expf(v6); tv[6] = (c == tl[6]) ? v6 : tv[6];
        s[7] += __expf(v7); tv[7] = (c == tl[7]) ? v7 : tv[7];
    }
    float ce = 0.0f;
    #pragma unroll
    for (int l = 0; l < L_; ++l) ce += __logf(s[l]) - tv[l];
    float cost_string = ce * (1.0f / L_);

    // ---------- class cost: -softmax(logits)[plate_type] ----------
    float x[C_];
    {
        const float4* lg = (const float4*)(logits + (size_t)idx * C_);
        float4 q0 = lg[0], q1 = lg[1], q2 = lg[2], q3 = lg[3];
        x[0]=q0.x; x[1]=q0.y; x[2]=q0.z; x[3]=q0.w;
        x[4]=q1.x; x[5]=q1.y; x[6]=q1.z; x[7]=q1.w;
        x[8]=q2.x; x[9]=q2.y; x[10]=q2.z; x[11]=q2.w;
        x[12]=q3.x; x[13]=q3.y; x[14]=q3.z; x[15]=q3.w;
    }
    int tcls = ptype[b];
    float m = x[0];
    #pragma unroll
    for (int i = 1; i < C_; ++i) m = fmaxf(m, x[i]);
    float se = 0.0f, xt = 0.0f;
    #pragma unroll
    for (int i = 0; i < C_; ++i) {
        se += __expf(x[i] - m);
        xt = (i == tcls) ? x[i] : xt;   // static index into x[], runtime select
    }
    float cost_class = -__expf(xt - m) / se;

    // ---------- bbox: vertices -> xyxy, L1, GIoU ----------
    float4 tb = *(const float4*)(tgt + b * 4);
    const float4* bx = (const float4*)(boxes + (size_t)idx * 8);
    float4 w0 = bx[0], w1 = bx[1];
    float px1 = fminf(fminf(w0.x, w0.z), fminf(w1.x, w1.z));
    float py1 = fminf(fminf(w0.y, w0.w), fminf(w1.y, w1.w));
    float px2 = fmaxf(fmaxf(w0.x, w0.z), fmaxf(w1.x, w1.z));
    float py2 = fmaxf(fmaxf(w0.y, w0.w), fmaxf(w1.y, w1.w));

    float cost_bbox = fabsf(px1 - tb.x) + fabsf(py1 - tb.y)
                    + fabsf(px2 - tb.z) + fabsf(py2 - tb.w);

    float ltx = fmaxf(px1, tb.x), lty = fmaxf(py1, tb.y);
    float rbx = fminf(px2, tb.z), rby = fminf(py2, tb.w);
    float iw = fmaxf(rbx - ltx, 0.0f), ih = fmaxf(rby - lty, 0.0f);
    float inter = iw * ih;
    float area_p = (px2 - px1) * (py2 - py1);
    float area_t = (tb.z - tb.x) * (tb.w - tb.y);
    float uni = area_p + area_t - inter;
    float iou = inter / uni;
    float cx1 = fminf(px1, tb.x), cy1 = fminf(py1, tb.y);
    float cx2 = fmaxf(px2, tb.z), cy2 = fmaxf(py2, tb.w);
    float cw = fmaxf(cx2 - cx1, 0.0f), ch = fmaxf(cy2 - cy1, 0.0f);
    float area_c = cw * ch;
    float giou = iou - (area_c - uni) / area_c;

    cost[idx] = cost_class + 5.0f * cost_bbox - 2.0f * giou + 10.0f * cost_string;
}

// K2: argmin over N per b with first-index tie-break (jnp.argmin semantics).
__global__ __launch_bounds__(256) void argmin_kernel(
    const float* __restrict__ cost, int* __restrict__ out)
{
    int b = blockIdx.x;
    int t = threadIdx.x;
    const float* cb = cost + b * N_;
    float bv = 3.4e38f;
    int bi = 0;
    for (int n = t; n < N_; n += 256) {
        float v = cb[n];
        if (v < bv) { bv = v; bi = n; }   // strict < keeps earliest within thread
    }
    __shared__ float sv[256];
    __shared__ int   si[256];
    sv[t] = bv; si[t] = bi;
    __syncthreads();
    for (int off = 128; off > 0; off >>= 1) {
        if (t < off) {
            float v2 = sv[t + off]; int i2 = si[t + off];
            if (v2 < sv[t] || (v2 == sv[t] && i2 < si[t])) { sv[t] = v2; si[t] = i2; }
        }
        __syncthreads();
    }
    if (t == 0) out[b] = si[0];
}

extern "C" void kernel_launch(void* const* d_in, const int* in_sizes, int n_in,
                              void* d_out, int out_size, void* d_ws, size_t ws_size,
                              hipStream_t stream) {
    const float* logits = (const float*)d_in[0];   // pred_logits [B,N,C]
    const float* boxes  = (const float*)d_in[1];   // pred_boxes  [B,N,8]
    const float* ps     = (const float*)d_in[2];   // pred_string_logits [B,75,N,8]
    const float* tgt    = (const float*)d_in[3];   // tgt_bboxes [B,4]
    const int*   ptype  = (const int*)d_in[4];     // plate_type [B]
    const int*   lps    = (const int*)d_in[5];     // lps [B,L]

    float* cost = (float*)d_ws;                    // [B,N] = 57600 floats
    int*   out  = (int*)d_out;                     // [B,1] int32

    cost_kernel<<<(B_ * N_ + 63) / 64, 64, 0, stream>>>(
        logits, boxes, ps, tgt, ptype, lps, cost);
    argmin_kernel<<<B_, 256, 0, stream>>>(cost, out);
}